// Round 1
// 666.294 us; speedup vs baseline: 2.5514x; 2.5514x over previous
//
#include <hip/hip_runtime.h>

#define BB 4
#define CC 128
#define CQ 16
#define TDIM 16
#define SS 65536            /* T*W*H */
#define CS (CC*SS)          /* per-batch elements: 8388608 */
#define NBLK 256            /* stage-1 partial blocks */

typedef unsigned short u16;
typedef unsigned int   u32;

typedef __bf16 bf16x8v __attribute__((ext_vector_type(8)));
typedef float  floatx4v __attribute__((ext_vector_type(4)));

__device__ __forceinline__ u16 f2bf(float f) {
    u32 u = __float_as_uint(f);
    u32 r = (u + 0x7fffu + ((u >> 16) & 1u)) >> 16;
    return (u16)r;
}
__device__ __forceinline__ void unpack8(uint4 r, float* f) {
    f[0] = __uint_as_float(r.x << 16); f[1] = __uint_as_float(r.x & 0xffff0000u);
    f[2] = __uint_as_float(r.y << 16); f[3] = __uint_as_float(r.y & 0xffff0000u);
    f[4] = __uint_as_float(r.z << 16); f[5] = __uint_as_float(r.z & 0xffff0000u);
    f[6] = __uint_as_float(r.w << 16); f[7] = __uint_as_float(r.w & 0xffff0000u);
}
__device__ __forceinline__ bf16x8v ld_bf8(const void* p) {
    union { uint4 u; bf16x8v b; } x;
    x.u = *(const uint4*)p;
    return x.b;
}

// ---------------------------------------------------------------------------
// Weight pre-convert: all 3 cells' [Wq;Wk;Wv] -> bf16 [3][160][128] + fp32 bias[3][160]
// ---------------------------------------------------------------------------
__global__ __launch_bounds__(256) void wconv_kernel(
    const float* __restrict__ Wq, const float* __restrict__ Wk, const float* __restrict__ Wv,
    const float* __restrict__ bq, const float* __restrict__ bk, const float* __restrict__ bv,
    u16* __restrict__ wbf, float* __restrict__ bias)
{
    const int idx = blockIdx.x * 256 + threadIdx.x;     // < 61440
    const int cell = idx / 20480;
    const int j = idx - cell * 20480;
    const int o = j >> 7, c = j & 127;
    float v;
    if (o < 16)      v = Wq[(cell * 16 + o) * 128 + c];
    else if (o < 32) v = Wk[(cell * 16 + (o - 16)) * 128 + c];
    else             v = Wv[(cell * 128 + (o - 32)) * 128 + c];
    wbf[idx] = f2bf(v);
    if (idx < 480) {
        const int cl = idx / 160, oo = idx - cl * 160;
        float b = (oo < 16) ? bq[cl * 16 + oo]
                : (oo < 32) ? bk[cl * 16 + oo - 16]
                :             bv[cl * 128 + oo - 32];
        bias[idx] = b;
    }
}

// ---------------------------------------------------------------------------
// QKV 1x1 conv as bf16 MFMA GEMM: out(160,S) = W(160,128) x X(128,S).
// Block = 256 thr (4 waves), S-tile 128. Wave (mh,sh): 5 m-tiles x 64 s.
// x tile staged transposed [s][c] bf16 in LDS, XOR-swizzled (^((s&7)<<4)).
// q,k -> fp32 (cq,S); v -> bf16 (c,S). batch = blockIdx.y.
// ---------------------------------------------------------------------------
__global__ __launch_bounds__(256, 2) void qkv_mfma_kernel(
    const float* __restrict__ x,
    const u16* __restrict__ wbf, const float* __restrict__ bias,
    float* __restrict__ qf, float* __restrict__ kf, u16* __restrict__ vf)
{
    __shared__ u16 xT[128 * 128];                      // 32 KB
    const int t  = threadIdx.x;
    const int b  = blockIdx.y;
    const int s0 = blockIdx.x << 7;
    const float* xb = x + (size_t)b * CS;

    {   // stage: transpose + bf16 convert. thread: s_loc = t&127, c-octet (t>>7)*8
        const int sl = t & 127;
        const int cb = (t >> 7) << 3;
        const float* xs = xb + s0 + sl;
        const u32 rowb = (u32)sl << 8;
        const u32 swz  = (u32)(sl & 7) << 4;
#pragma unroll 2
        for (int p = 0; p < 8; p++) {
            const int c0 = p * 16 + cb;
            float f[8];
#pragma unroll
            for (int j = 0; j < 8; j++) f[j] = xs[(size_t)(c0 + j) * SS];
            uint4 pk;
            pk.x = (u32)f2bf(f[0]) | ((u32)f2bf(f[1]) << 16);
            pk.y = (u32)f2bf(f[2]) | ((u32)f2bf(f[3]) << 16);
            pk.z = (u32)f2bf(f[4]) | ((u32)f2bf(f[5]) << 16);
            pk.w = (u32)f2bf(f[6]) | ((u32)f2bf(f[7]) << 16);
            *(uint4*)((char*)xT + ((rowb + (u32)(c0 << 1)) ^ swz)) = pk;
        }
    }
    __syncthreads();

    const int lane = t & 63;
    const int wv   = t >> 6;
    const int mh   = wv >> 1;          // m-tiles mh*5 .. mh*5+4  (rows mh*80..)
    const int sh   = wv & 1;           // s offset sh*64
    const int ln15 = lane & 15;
    const int lhi  = lane >> 4;        // 0..3

    floatx4v acc[5][4] = {};

    const u16* abase = wbf + ((mh * 80 + ln15) << 7) + (lhi << 3);
    const u32 swzB = (u32)(ln15 & 7) << 4;   // (s_loc&7) is ln15&7 for all nt
    const int sbase = sh * 64 + ln15;

#pragma unroll
    for (int ks = 0; ks < 4; ks++) {
        bf16x8v af[5];
#pragma unroll
        for (int mi = 0; mi < 5; mi++)
            af[mi] = ld_bf8(abase + (mi << 11) + (ks << 5));
#pragma unroll
        for (int nt = 0; nt < 4; nt++) {
            const u32 off = (((u32)(sbase + nt * 16) << 8)
                           + (u32)((ks << 6) + (lhi << 4))) ^ swzB;
            bf16x8v bf = ld_bf8((const char*)xT + off);
#pragma unroll
            for (int mi = 0; mi < 5; mi++)
                acc[mi][nt] = __builtin_amdgcn_mfma_f32_16x16x32_bf16(
                                  af[mi], bf, acc[mi][nt], 0, 0, 0);
        }
    }

    float* qb = qf + (size_t)b * ((size_t)CQ * SS);
    float* kb = kf + (size_t)b * ((size_t)CQ * SS);
    u16*   vb = vf + (size_t)b * (size_t)CS;

#pragma unroll
    for (int mi = 0; mi < 5; mi++) {
        const int o0 = mh * 80 + mi * 16 + lhi * 4;    // D row = o0 + r, col = ln15
        float bia[4];
        *(float4*)bia = *(const float4*)(bias + o0);
#pragma unroll
        for (int nt = 0; nt < 4; nt++) {
            const int s = s0 + sh * 64 + nt * 16 + ln15;
            if (o0 < 16) {
#pragma unroll
                for (int r = 0; r < 4; r++)
                    qb[(size_t)(o0 + r) * SS + s] = acc[mi][nt][r] + bia[r];
            } else if (o0 < 32) {
#pragma unroll
                for (int r = 0; r < 4; r++)
                    kb[(size_t)(o0 - 16 + r) * SS + s] = acc[mi][nt][r] + bia[r];
            } else {
#pragma unroll
                for (int r = 0; r < 4; r++)
                    vb[(size_t)(o0 - 32 + r) * SS + s] = f2bf(acc[mi][nt][r] + bia[r]);
            }
        }
    }
}

// ---------------------------------------------------------------------------
// Stage 1: per-block partial logits (layouts unchanged from verified version).
// part[blk]: A=64 -> t*16+j encodes (a1=t&63, a2=(t>>6)*16+j); A=16 -> t = a1*16+a2.
// ---------------------------------------------------------------------------
template <int A>
__global__ __launch_bounds__(256) void logits_part_kernel(
    const float* __restrict__ qf, const float* __restrict__ kf,
    float* __restrict__ part)
{
    constexpr int N = (CQ * SS) / A;
    constexpr int NCHUNK = N / NBLK;
    constexpr int NLOG = (NCHUNK == 64) ? 6 : 8;
    __shared__ float qs[A][NCHUNK + 1];
    __shared__ float ks[NCHUNK][A];
    const int t  = threadIdx.x;
    const int b  = blockIdx.y;
    const int n0 = blockIdx.x << NLOG;
    const float* qb = qf + (size_t)b * ((size_t)CQ * SS);
    const float* kb = kf + (size_t)b * ((size_t)CQ * SS);

    for (int idx = t; idx < A * NCHUNK; idx += 256) {
        int a1 = idx >> NLOG, n = idx & (NCHUNK - 1);
        qs[a1][n] = qb[(size_t)a1 * N + n0 + n];
    }
    float* ksf = &ks[0][0];
    for (int idx = t; idx < NCHUNK * A; idx += 256)
        ksf[idx] = kb[(size_t)n0 * A + idx];
    __syncthreads();

    float* pb = part + ((size_t)b * NBLK + blockIdx.x) * (A * A);

    if constexpr (A == 16) {
        int a1 = t >> 4, a2 = t & 15;
        float s = 0.f;
#pragma unroll 8
        for (int n = 0; n < NCHUNK; n++) s += qs[a1][n] * ks[n][a2];
        pb[t] = s;
    } else {
        int a1  = t & 63;
        int a2b = (t >> 6) * 16;
        float acc[16];
#pragma unroll
        for (int j = 0; j < 16; j++) acc[j] = 0.f;
        for (int n = 0; n < NCHUNK; n++) {
            float q = qs[a1][n];
#pragma unroll
            for (int j = 0; j < 16; j++) acc[j] += q * ks[n][a2b + j];
        }
        float* dst = pb + t * 16;
        *(float4*)(dst)      = make_float4(acc[0],  acc[1],  acc[2],  acc[3]);
        *(float4*)(dst + 4)  = make_float4(acc[4],  acc[5],  acc[6],  acc[7]);
        *(float4*)(dst + 8)  = make_float4(acc[8],  acc[9],  acc[10], acc[11]);
        *(float4*)(dst + 12) = make_float4(acc[12], acc[13], acc[14], acc[15]);
    }
}

// ---------------------------------------------------------------------------
// Stage 2: reduce partials + softmax. grid=(A, nb), block=256 (NG parallel groups).
// ---------------------------------------------------------------------------
template <int A>
__global__ __launch_bounds__(256) void reduce_softmax_kernel(
    const float* __restrict__ part, float* __restrict__ attn)
{
    constexpr int NG = 256 / A;              // 16 (A=16) or 4 (A=64)
    __shared__ float red[NG][A];
    const int a1 = blockIdx.x;
    const int b  = blockIdx.y;
    const int t  = threadIdx.x;
    const int a2 = t & (A - 1);
    const int g  = t >> ((A == 16) ? 4 : 6);
    const float* pb = part + (size_t)b * NBLK * (A * A);

    int off;
    if constexpr (A == 16) off = a1 * 16 + a2;
    else                   off = a1 * 16 + ((a2 >> 4) << 10) + (a2 & 15);

    float s0 = 0.f, s1 = 0.f, s2 = 0.f, s3 = 0.f;
    for (int blk = g; blk < NBLK; blk += 4 * NG) {
        s0 += pb[(size_t)(blk         ) * (A * A) + off];
        s1 += pb[(size_t)(blk +     NG) * (A * A) + off];
        s2 += pb[(size_t)(blk + 2 * NG) * (A * A) + off];
        s3 += pb[(size_t)(blk + 3 * NG) * (A * A) + off];
    }
    red[g][a2] = (s0 + s1) + (s2 + s3);
    __syncthreads();

    if (t < A) {
        float l = 0.f;
#pragma unroll
        for (int gg = 0; gg < NG; gg++) l += red[gg][t];
        float m = l;
#pragma unroll
        for (int o2 = A / 2; o2 > 0; o2 >>= 1) m = fmaxf(m, __shfl_xor(m, o2, 64));
        float e = expf(l - m);
        float s = e;
#pragma unroll
        for (int o2 = A / 2; o2 > 0; o2 >>= 1) s += __shfl_xor(s, o2, 64);
        attn[((size_t)b << 12) + a1 * A + t] = e / s;
    }
}

// ---------------------------------------------------------------------------
// Out, A=16 (cell T). Thread owns v-row m=(c,w,h), sweeps all 16 t outputs.
// v-row read ONCE per 16 outputs (was 16x redundant).
// ---------------------------------------------------------------------------
__global__ __launch_bounds__(256) void out16_kernel(
    const float* __restrict__ x, const u16* __restrict__ vf,
    const float* __restrict__ attn, const float* __restrict__ gptr,
    float* __restrict__ y)
{
    const int b = blockIdx.y;
    const u32 u = blockIdx.x * 256u + threadIdx.x;   // < CS/16 = 524288
    const float g = *gptr;
    const float* ab = attn + ((size_t)b << 12);
    const float* xb = x + (size_t)b * CS;
    float*       yb = y + (size_t)b * CS;
    const u16*   vr = vf + (size_t)b * CS + (size_t)u * 16;

    uint4 r0 = *(const uint4*)(vr);
    uint4 r1 = *(const uint4*)(vr + 8);
    float v0[8], v1[8];
    unpack8(r0, v0); unpack8(r1, v1);

    const size_t base = ((size_t)(u >> 12) << 16) + (u & 4095u);  // c*65536 + w*64 + h
#pragma unroll
    for (int tt = 0; tt < 16; tt++) {
        const float* ar = ab + tt * 16;
        float4 a0 = *(const float4*)(ar);
        float4 a1 = *(const float4*)(ar + 4);
        float4 a2 = *(const float4*)(ar + 8);
        float4 a3 = *(const float4*)(ar + 12);
        float acc = v0[0]*a0.x + v0[1]*a0.y + v0[2]*a0.z + v0[3]*a0.w
                  + v0[4]*a1.x + v0[5]*a1.y + v0[6]*a1.z + v0[7]*a1.w
                  + v1[0]*a2.x + v1[1]*a2.y + v1[2]*a2.z + v1[3]*a2.w
                  + v1[4]*a3.x + v1[5]*a3.y + v1[6]*a3.z + v1[7]*a3.w;
        const size_t i = base + ((size_t)tt << 12);
        yb[i] = g * acc + xb[i];
    }
}

// ---------------------------------------------------------------------------
// Out, A=64 (cells W,H). Thread owns (n = c*1024+w*16+(h>>2), hlow = h&3):
// 16 outputs (t=0..15), a1 = hlow*16+t. attn staged in LDS, XOR-swizzled so the
// 4 distinct a1 rows per instr hit different bank-quads.
// ---------------------------------------------------------------------------
__device__ __forceinline__ u32 atoff(int r, int c) {
    return (((u32)r << 8) + ((u32)c << 2)) ^ (((u32)(r >> 4) & 3u) << 4);
}

__global__ __launch_bounds__(256) void out64_kernel(
    const float* __restrict__ x, const u16* __restrict__ vf,
    const float* __restrict__ attn, const float* __restrict__ gptr,
    float* __restrict__ y)
{
    __shared__ float atf[4096];                        // 16 KB, swizzled
    const int b = blockIdx.y;
    const int t = threadIdx.x;
    const float g = *gptr;
    const float* ab = attn + ((size_t)b << 12);
    {
        char* atb = (char*)atf;
        for (int idx = t; idx < 4096; idx += 256)
            *(float*)(atb + atoff(idx >> 6, idx & 63)) = ab[idx];
    }
    __syncthreads();

    const u32 u   = blockIdx.x * 256u + t;             // < CS/16 = 524288
    const int hlow = u & 3;
    const int h2   = (u >> 2) & 15;
    const int w    = (u >> 6) & 63;
    const int c    = u >> 12;
    const int n    = (c << 10) + (w << 4) + h2;

    const u16*   vr = vf + (size_t)b * CS + (size_t)n * 64;
    const float* xb = x + (size_t)b * CS;
    float*       yb = y + (size_t)b * CS;

    float acc[16];
#pragma unroll
    for (int i = 0; i < 16; i++) acc[i] = 0.f;

    const char* atb = (const char*)atf;
#pragma unroll
    for (int a2b = 0; a2b < 64; a2b += 8) {
        uint4 rv = *(const uint4*)(vr + a2b);
        float v[8];
        unpack8(rv, v);
#pragma unroll
        for (int tt = 0; tt < 16; tt++) {
            const int r = hlow * 16 + tt;
            float4 p0 = *(const float4*)(atb + atoff(r, a2b));
            float4 p1 = *(const float4*)(atb + atoff(r, a2b + 4));
            acc[tt] += v[0]*p0.x + v[1]*p0.y + v[2]*p0.z + v[3]*p0.w
                     + v[4]*p1.x + v[5]*p1.y + v[6]*p1.z + v[7]*p1.w;
        }
    }

    const size_t base = ((size_t)c << 16) + ((u32)w << 6) + (h2 << 2) + hlow;
#pragma unroll
    for (int tt = 0; tt < 16; tt++) {
        const size_t i = base + ((size_t)tt << 12);
        yb[i] = g * acc[tt] + xb[i];
    }
}

// ---------------------------------------------------------------------------
// Workspace (nb batches resident): qf nb*4M | kf nb*4M | vf nb*16M |
// part nb*4M | attn nb*16K | wbf3 120K | bias3 2K.  nb=4 needs ~112.2 MiB;
// falls back to nb=1 (per-batch loop) if ws is smaller.
// ---------------------------------------------------------------------------
extern "C" void kernel_launch(void* const* d_in, const int* in_sizes, int n_in,
                              void* d_out, int out_size, void* d_ws, size_t ws_size,
                              hipStream_t stream)
{
    (void)in_sizes; (void)n_in; (void)out_size;
    const float* x0    = (const float*)d_in[0];
    const float* Wq    = (const float*)d_in[1];
    const float* bq    = (const float*)d_in[2];
    const float* Wk    = (const float*)d_in[3];
    const float* bk    = (const float*)d_in[4];
    const float* Wv    = (const float*)d_in[5];
    const float* bv    = (const float*)d_in[6];
    const float* gamma = (const float*)d_in[7];
    float* y = (float*)d_out;

    const size_t MiB = (size_t)1 << 20;
    const size_t need4 = 4 * (28 * MiB + 16384) + 160 * 128 * 3 * 2 + 3 * 160 * 4;
    const int nb = (ws_size >= need4) ? 4 : 1;

    char* ws = (char*)d_ws;
    float* qf    = (float*)ws;
    float* kf    = (float*)(ws + (size_t)nb * 4  * MiB);
    u16*   vf    = (u16*)  (ws + (size_t)nb * 8  * MiB);
    float* part  = (float*)(ws + (size_t)nb * 24 * MiB);
    float* attnp = (float*)(ws + (size_t)nb * 28 * MiB);
    u16*   wbf3  = (u16*)  (ws + (size_t)nb * 28 * MiB + (size_t)nb * 16384);
    float* bias3 = (float*)(ws + (size_t)nb * 28 * MiB + (size_t)nb * 16384
                               + 160 * 128 * 3 * 2);

    wconv_kernel<<<240, 256, 0, stream>>>(Wq, Wk, Wv, bq, bk, bv, wbf3, bias3);

    for (int cell = 0; cell < 3; cell++) {
        const u16*   wc = wbf3  + (size_t)cell * 160 * 128;
        const float* bc = bias3 + (size_t)cell * 160;
        for (int b0 = 0; b0 < BB; b0 += nb) {
            const float* xin = ((cell == 0) ? x0 : (const float*)y) + (size_t)b0 * CS;
            float* yb = y + (size_t)b0 * CS;

            qkv_mfma_kernel<<<dim3(512, nb), 256, 0, stream>>>(xin, wc, bc, qf, kf, vf);

            if (cell == 0) {
                logits_part_kernel<16><<<dim3(NBLK, nb), 256, 0, stream>>>(qf, kf, part);
                reduce_softmax_kernel<16><<<dim3(16, nb), 256, 0, stream>>>(part, attnp);
                out16_kernel<<<dim3(2048, nb), 256, 0, stream>>>(xin, vf, attnp, gamma + cell, yb);
            } else {
                logits_part_kernel<64><<<dim3(NBLK, nb), 256, 0, stream>>>(qf, kf, part);
                reduce_softmax_kernel<64><<<dim3(64, nb), 256, 0, stream>>>(part, attnp);
                out64_kernel<<<dim3(2048, nb), 256, 0, stream>>>(xin, vf, attnp, gamma + cell, yb);
            }
        }
    }
}

// Round 2
// 630.099 us; speedup vs baseline: 2.6979x; 1.0574x over previous
//
#include <hip/hip_runtime.h>

#define BB 4
#define CC 128
#define CQ 16
#define TDIM 16
#define SS 65536            /* T*W*H */
#define CS (CC*SS)          /* per-batch elements: 8388608 */
#define NBLK 256            /* stage-1 partial blocks */

typedef unsigned short u16;
typedef unsigned int   u32;

typedef __bf16 bf16x8v __attribute__((ext_vector_type(8)));
typedef float  floatx4v __attribute__((ext_vector_type(4)));

__device__ __forceinline__ u16 f2bf(float f) {
    u32 u = __float_as_uint(f);
    u32 r = (u + 0x7fffu + ((u >> 16) & 1u)) >> 16;
    return (u16)r;
}
__device__ __forceinline__ void unpack8(uint4 r, float* f) {
    f[0] = __uint_as_float(r.x << 16); f[1] = __uint_as_float(r.x & 0xffff0000u);
    f[2] = __uint_as_float(r.y << 16); f[3] = __uint_as_float(r.y & 0xffff0000u);
    f[4] = __uint_as_float(r.z << 16); f[5] = __uint_as_float(r.z & 0xffff0000u);
    f[6] = __uint_as_float(r.w << 16); f[7] = __uint_as_float(r.w & 0xffff0000u);
}
__device__ __forceinline__ bf16x8v ld_bf8(const void* p) {
    union { uint4 u; bf16x8v b; } x;
    x.u = *(const uint4*)p;
    return x.b;
}

// ---------------------------------------------------------------------------
// Weight pre-convert: all 3 cells' [Wq;Wk;Wv] -> bf16 [3][160][128] + fp32 bias[3][160]
// ---------------------------------------------------------------------------
__global__ __launch_bounds__(256) void wconv_kernel(
    const float* __restrict__ Wq, const float* __restrict__ Wk, const float* __restrict__ Wv,
    const float* __restrict__ bq, const float* __restrict__ bk, const float* __restrict__ bv,
    u16* __restrict__ wbf, float* __restrict__ bias)
{
    const int idx = blockIdx.x * 256 + threadIdx.x;     // < 61440
    const int cell = idx / 20480;
    const int j = idx - cell * 20480;
    const int o = j >> 7, c = j & 127;
    float v;
    if (o < 16)      v = Wq[(cell * 16 + o) * 128 + c];
    else if (o < 32) v = Wk[(cell * 16 + (o - 16)) * 128 + c];
    else             v = Wv[(cell * 128 + (o - 32)) * 128 + c];
    wbf[idx] = f2bf(v);
    if (idx < 480) {
        const int cl = idx / 160, oo = idx - cl * 160;
        float b = (oo < 16) ? bq[cl * 16 + oo]
                : (oo < 32) ? bk[cl * 16 + oo - 16]
                :             bv[cl * 128 + oo - 32];
        bias[idx] = b;
    }
}

// ---------------------------------------------------------------------------
// QKV 1x1 conv as bf16 MFMA GEMM: out(160,S) = W(160,128) x X(128,S).
// Block = 512 thr (8 waves), S-tile 128. Wave (mh = wv>>2, sq = wv&3):
// 5 m-tiles (rows mh*80..) x 32 s (2 subtiles of 16 at sq*32).
// x tile staged transposed [s][c] bf16 in LDS, XOR-swizzled (^((s&7)<<4)).
// q,k -> fp32 (cq,S); v -> bf16 (c,S). batch = blockIdx.y.
// ---------------------------------------------------------------------------
__global__ __launch_bounds__(512, 4) void qkv_mfma_kernel(
    const float* __restrict__ x,
    const u16* __restrict__ wbf, const float* __restrict__ bias,
    float* __restrict__ qf, float* __restrict__ kf, u16* __restrict__ vf)
{
    __shared__ u16 xT[128 * 128];                      // 32 KB
    const int t  = threadIdx.x;
    const int b  = blockIdx.y;
    const int s0 = blockIdx.x << 7;
    const float* xb = x + (size_t)b * CS;

    {   // stage: thread owns s-row sl = t&127, c-octets cb, cb+32, cb+64, cb+96
        const int sl = t & 127;
        const int cb = (t >> 7) << 3;
        const float* xs = xb + s0 + sl;
        const u32 rowb = (u32)sl << 8;
        const u32 swz  = (u32)(sl & 7) << 4;
#pragma unroll
        for (int p = 0; p < 4; p++) {
            const int c0 = p * 32 + cb;
            float f[8];
#pragma unroll
            for (int j = 0; j < 8; j++) f[j] = xs[(size_t)(c0 + j) * SS];
            uint4 pk;
            pk.x = (u32)f2bf(f[0]) | ((u32)f2bf(f[1]) << 16);
            pk.y = (u32)f2bf(f[2]) | ((u32)f2bf(f[3]) << 16);
            pk.z = (u32)f2bf(f[4]) | ((u32)f2bf(f[5]) << 16);
            pk.w = (u32)f2bf(f[6]) | ((u32)f2bf(f[7]) << 16);
            *(uint4*)((char*)xT + ((rowb + (u32)(c0 << 1)) ^ swz)) = pk;
        }
    }
    __syncthreads();

    const int lane = t & 63;
    const int wv   = t >> 6;           // 0..7
    const int mh   = wv >> 2;          // 0,1 -> rows mh*80..
    const int sq   = wv & 3;           // s offset sq*32
    const int ln15 = lane & 15;
    const int lhi  = lane >> 4;        // 0..3

    floatx4v acc[5][2] = {};

    const u16* abase = wbf + ((mh * 80 + ln15) << 7) + (lhi << 3);
    const u32 swzB = (u32)(ln15 & 7) << 4;   // (s&7) == ln15&7 for both nt
    const int sbase = sq * 32 + ln15;

#pragma unroll
    for (int ks = 0; ks < 4; ks++) {
        bf16x8v af[5];
#pragma unroll
        for (int mi = 0; mi < 5; mi++)
            af[mi] = ld_bf8(abase + (mi << 11) + (ks << 5));
#pragma unroll
        for (int nt = 0; nt < 2; nt++) {
            const u32 off = (((u32)(sbase + nt * 16) << 8)
                           + (u32)((ks << 6) + (lhi << 4))) ^ swzB;
            bf16x8v bf = ld_bf8((const char*)xT + off);
#pragma unroll
            for (int mi = 0; mi < 5; mi++)
                acc[mi][nt] = __builtin_amdgcn_mfma_f32_16x16x32_bf16(
                                  af[mi], bf, acc[mi][nt], 0, 0, 0);
        }
    }

    float* qb = qf + (size_t)b * ((size_t)CQ * SS);
    float* kb = kf + (size_t)b * ((size_t)CQ * SS);
    u16*   vb = vf + (size_t)b * (size_t)CS;

#pragma unroll
    for (int mi = 0; mi < 5; mi++) {
        const int o0 = mh * 80 + mi * 16 + lhi * 4;    // D row = o0 + r, col = ln15
        float bia[4];
        *(float4*)bia = *(const float4*)(bias + o0);
#pragma unroll
        for (int nt = 0; nt < 2; nt++) {
            const int s = s0 + sq * 32 + nt * 16 + ln15;
            if (o0 < 16) {
#pragma unroll
                for (int r = 0; r < 4; r++)
                    qb[(size_t)(o0 + r) * SS + s] = acc[mi][nt][r] + bia[r];
            } else if (o0 < 32) {
#pragma unroll
                for (int r = 0; r < 4; r++)
                    kb[(size_t)(o0 - 16 + r) * SS + s] = acc[mi][nt][r] + bia[r];
            } else {
#pragma unroll
                for (int r = 0; r < 4; r++)
                    vb[(size_t)(o0 - 32 + r) * SS + s] = f2bf(acc[mi][nt][r] + bia[r]);
            }
        }
    }
}

// ---------------------------------------------------------------------------
// Stage 1: per-block partial logits (layouts unchanged from verified version).
// part[blk]: A=64 -> t*16+j encodes (a1=t&63, a2=(t>>6)*16+j); A=16 -> t = a1*16+a2.
// ---------------------------------------------------------------------------
template <int A>
__global__ __launch_bounds__(256) void logits_part_kernel(
    const float* __restrict__ qf, const float* __restrict__ kf,
    float* __restrict__ part)
{
    constexpr int N = (CQ * SS) / A;
    constexpr int NCHUNK = N / NBLK;
    constexpr int NLOG = (NCHUNK == 64) ? 6 : 8;
    __shared__ float qs[A][NCHUNK + 1];
    __shared__ float ks[NCHUNK][A];
    const int t  = threadIdx.x;
    const int b  = blockIdx.y;
    const int n0 = blockIdx.x << NLOG;
    const float* qb = qf + (size_t)b * ((size_t)CQ * SS);
    const float* kb = kf + (size_t)b * ((size_t)CQ * SS);

    for (int idx = t; idx < A * NCHUNK; idx += 256) {
        int a1 = idx >> NLOG, n = idx & (NCHUNK - 1);
        qs[a1][n] = qb[(size_t)a1 * N + n0 + n];
    }
    float* ksf = &ks[0][0];
    for (int idx = t; idx < NCHUNK * A; idx += 256)
        ksf[idx] = kb[(size_t)n0 * A + idx];
    __syncthreads();

    float* pb = part + ((size_t)b * NBLK + blockIdx.x) * (A * A);

    if constexpr (A == 16) {
        int a1 = t >> 4, a2 = t & 15;
        float s = 0.f;
#pragma unroll 8
        for (int n = 0; n < NCHUNK; n++) s += qs[a1][n] * ks[n][a2];
        pb[t] = s;
    } else {
        int a1  = t & 63;
        int a2b = (t >> 6) * 16;
        float acc[16];
#pragma unroll
        for (int j = 0; j < 16; j++) acc[j] = 0.f;
        for (int n = 0; n < NCHUNK; n++) {
            float q = qs[a1][n];
#pragma unroll
            for (int j = 0; j < 16; j++) acc[j] += q * ks[n][a2b + j];
        }
        float* dst = pb + t * 16;
        *(float4*)(dst)      = make_float4(acc[0],  acc[1],  acc[2],  acc[3]);
        *(float4*)(dst + 4)  = make_float4(acc[4],  acc[5],  acc[6],  acc[7]);
        *(float4*)(dst + 8)  = make_float4(acc[8],  acc[9],  acc[10], acc[11]);
        *(float4*)(dst + 12) = make_float4(acc[12], acc[13], acc[14], acc[15]);
    }
}

// ---------------------------------------------------------------------------
// Stage 2: reduce partials + softmax. grid=(A, nb), block=256 (NG parallel groups).
// A=64 additionally emits bf16 attn (for the MFMA out kernel).
// ---------------------------------------------------------------------------
template <int A>
__global__ __launch_bounds__(256) void reduce_softmax_kernel(
    const float* __restrict__ part, float* __restrict__ attn, u16* __restrict__ pbf)
{
    constexpr int NG = 256 / A;              // 16 (A=16) or 4 (A=64)
    __shared__ float red[NG][A];
    const int a1 = blockIdx.x;
    const int b  = blockIdx.y;
    const int t  = threadIdx.x;
    const int a2 = t & (A - 1);
    const int g  = t >> ((A == 16) ? 4 : 6);
    const float* pb = part + (size_t)b * NBLK * (A * A);

    int off;
    if constexpr (A == 16) off = a1 * 16 + a2;
    else                   off = a1 * 16 + ((a2 >> 4) << 10) + (a2 & 15);

    float s0 = 0.f, s1 = 0.f, s2 = 0.f, s3 = 0.f;
    for (int blk = g; blk < NBLK; blk += 4 * NG) {
        s0 += pb[(size_t)(blk         ) * (A * A) + off];
        s1 += pb[(size_t)(blk +     NG) * (A * A) + off];
        s2 += pb[(size_t)(blk + 2 * NG) * (A * A) + off];
        s3 += pb[(size_t)(blk + 3 * NG) * (A * A) + off];
    }
    red[g][a2] = (s0 + s1) + (s2 + s3);
    __syncthreads();

    if (t < A) {
        float l = 0.f;
#pragma unroll
        for (int gg = 0; gg < NG; gg++) l += red[gg][t];
        float m = l;
#pragma unroll
        for (int o2 = A / 2; o2 > 0; o2 >>= 1) m = fmaxf(m, __shfl_xor(m, o2, 64));
        float e = expf(l - m);
        float s = e;
#pragma unroll
        for (int o2 = A / 2; o2 > 0; o2 >>= 1) s += __shfl_xor(s, o2, 64);
        const float p = e / s;
        attn[((size_t)b << 12) + a1 * A + t] = p;
        if constexpr (A == 64)
            pbf[((size_t)b << 12) + a1 * 64 + t] = f2bf(p);
    }
}

// ---------------------------------------------------------------------------
// Out, A=16 (cell T). Thread owns v-row m=(c,w,h), sweeps all 16 t outputs.
// ---------------------------------------------------------------------------
__global__ __launch_bounds__(256) void out16_kernel(
    const float* __restrict__ x, const u16* __restrict__ vf,
    const float* __restrict__ attn, const float* __restrict__ gptr,
    float* __restrict__ y)
{
    const int b = blockIdx.y;
    const u32 u = blockIdx.x * 256u + threadIdx.x;   // < CS/16 = 524288
    const float g = *gptr;
    const float* ab = attn + ((size_t)b << 12);
    const float* xb = x + (size_t)b * CS;
    float*       yb = y + (size_t)b * CS;
    const u16*   vr = vf + (size_t)b * CS + (size_t)u * 16;

    uint4 r0 = *(const uint4*)(vr);
    uint4 r1 = *(const uint4*)(vr + 8);
    float v0[8], v1[8];
    unpack8(r0, v0); unpack8(r1, v1);

    const size_t base = ((size_t)(u >> 12) << 16) + (u & 4095u);  // c*65536 + w*64 + h
#pragma unroll
    for (int tt = 0; tt < 16; tt++) {
        const float* ar = ab + tt * 16;
        float4 a0 = *(const float4*)(ar);
        float4 a1 = *(const float4*)(ar + 4);
        float4 a2 = *(const float4*)(ar + 8);
        float4 a3 = *(const float4*)(ar + 12);
        float acc = v0[0]*a0.x + v0[1]*a0.y + v0[2]*a0.z + v0[3]*a0.w
                  + v0[4]*a1.x + v0[5]*a1.y + v0[6]*a1.z + v0[7]*a1.w
                  + v1[0]*a2.x + v1[1]*a2.y + v1[2]*a2.z + v1[3]*a2.w
                  + v1[4]*a3.x + v1[5]*a3.y + v1[6]*a3.z + v1[7]*a3.w;
        const size_t i = base + ((size_t)tt << 12);
        yb[i] = g * acc + xb[i];
    }
}

// ---------------------------------------------------------------------------
// Out, A=64 (cells W,H) via MFMA: O[m][a1] = sum_a2 V[m][a2] * P[a1][a2].
// m = c*1024 + t*64 + w_sp (V rows = 64 contiguous bf16 in vf).
// D[row=a1][col=m]: A-op = P (bf16, 64x64), B-op = V^T.
// y index: c*65536 + (a1&15)*4096 + ((m>>6)&15)*256... derived:
//   y = (m>>12 ... ) -- see store: y = c<<16 | ot<<12 | ow<<6 | (ln15*4 + sub)
// Wave: 4 consecutive m-tiles of 16 (64 m), all 64 a1. Block 256 = 4 waves = 256 m.
// ---------------------------------------------------------------------------
__global__ __launch_bounds__(256) void out64_mfma_kernel(
    const float* __restrict__ x, const u16* __restrict__ vf,
    const u16* __restrict__ pbf, const float* __restrict__ gptr,
    float* __restrict__ y)
{
    const int b = blockIdx.y;
    const int t = threadIdx.x;
    const float g = *gptr;
    const int lane = t & 63;
    const int ln15 = lane & 15;
    const int lhi  = lane >> 4;
    const int wv   = t >> 6;
    const int m0w  = blockIdx.x * 256 + wv * 64;

    const u16*   pb = pbf + ((size_t)b << 12);
    const u16*   vb = vf + (size_t)b * CS;
    const float* xb = x + (size_t)b * CS;
    float*       yb = y + (size_t)b * CS;

    // A-frags: P[a1 = sub*16 + ln15][k = ks*32 + lhi*8 + j]  (L1-hot, 8 x 16B)
    bf16x8v af[2][4];
#pragma unroll
    for (int ksi = 0; ksi < 2; ksi++)
#pragma unroll
        for (int sub = 0; sub < 4; sub++)
            af[ksi][sub] = ld_bf8(pb + (sub * 16 + ln15) * 64 + ksi * 32 + lhi * 8);

#pragma unroll
    for (int tile = 0; tile < 4; tile++) {
        const int m0 = m0w + tile * 16;
        const u16* vrow = vb + ((size_t)(m0 + ln15) << 6) + (lhi << 3);
        bf16x8v b0 = ld_bf8(vrow);          // k = 0..31  (per-lane map lhi*8+j)
        bf16x8v b1 = ld_bf8(vrow + 32);     // k = 32..63

        floatx4v acc[4] = {};
#pragma unroll
        for (int sub = 0; sub < 4; sub++) {
            acc[sub] = __builtin_amdgcn_mfma_f32_16x16x32_bf16(af[0][sub], b0, acc[sub], 0, 0, 0);
            acc[sub] = __builtin_amdgcn_mfma_f32_16x16x32_bf16(af[1][sub], b1, acc[sub], 0, 0, 0);
        }

        // m0 is 16-aligned: c = m0>>10, ti = (m0>>6)&15, whi = (m0&63)>>4
        const int c   = m0 >> 10;
        const int ow  = ((m0 >> 6) & 15) * 4 + ((m0 & 63) >> 4);
        const size_t base = ((size_t)c << 16) + ((size_t)ow << 6) + (size_t)(ln15 << 2);
        const float* xbase = xb + base;
        float*       ybase = yb + base;
#pragma unroll
        for (int r = 0; r < 4; r++) {
            const int ot = lhi * 4 + r;                 // a1 & 15
            float4 xv = *(const float4*)(xbase + ((size_t)ot << 12));
            float4 o;                                    // positions ln15*4 + sub
            o.x = g * acc[0][r] + xv.x;
            o.y = g * acc[1][r] + xv.y;
            o.z = g * acc[2][r] + xv.z;
            o.w = g * acc[3][r] + xv.w;
            *(float4*)(ybase + ((size_t)ot << 12)) = o;
        }
    }
}

// ---------------------------------------------------------------------------
// Workspace (nb batches resident): qf nb*4M | kf nb*4M | vf nb*16M |
// part nb*4M | attn nb*16K | pbf nb*8K | wbf3 120K | bias3 2K.
// nb=4 needs ~112.2 MiB; falls back to nb=1 if ws is smaller.
// ---------------------------------------------------------------------------
extern "C" void kernel_launch(void* const* d_in, const int* in_sizes, int n_in,
                              void* d_out, int out_size, void* d_ws, size_t ws_size,
                              hipStream_t stream)
{
    (void)in_sizes; (void)n_in; (void)out_size;
    const float* x0    = (const float*)d_in[0];
    const float* Wq    = (const float*)d_in[1];
    const float* bq    = (const float*)d_in[2];
    const float* Wk    = (const float*)d_in[3];
    const float* bk    = (const float*)d_in[4];
    const float* Wv    = (const float*)d_in[5];
    const float* bv    = (const float*)d_in[6];
    const float* gamma = (const float*)d_in[7];
    float* y = (float*)d_out;

    const size_t MiB = (size_t)1 << 20;
    const size_t need4 = 4 * (28 * MiB + 16384 + 8192) + 160 * 128 * 3 * 2 + 3 * 160 * 4;
    const int nb = (ws_size >= need4) ? 4 : 1;

    char* ws = (char*)d_ws;
    float* qf    = (float*)ws;
    float* kf    = (float*)(ws + (size_t)nb * 4  * MiB);
    u16*   vf    = (u16*)  (ws + (size_t)nb * 8  * MiB);
    float* part  = (float*)(ws + (size_t)nb * 24 * MiB);
    float* attnp = (float*)(ws + (size_t)nb * 28 * MiB);
    u16*   pbf   = (u16*)  (ws + (size_t)nb * 28 * MiB + (size_t)nb * 16384);
    u16*   wbf3  = (u16*)  (ws + (size_t)nb * 28 * MiB + (size_t)nb * (16384 + 8192));
    float* bias3 = (float*)(ws + (size_t)nb * 28 * MiB + (size_t)nb * (16384 + 8192)
                               + 160 * 128 * 3 * 2);

    wconv_kernel<<<240, 256, 0, stream>>>(Wq, Wk, Wv, bq, bk, bv, wbf3, bias3);

    for (int cell = 0; cell < 3; cell++) {
        const u16*   wc = wbf3  + (size_t)cell * 160 * 128;
        const float* bc = bias3 + (size_t)cell * 160;
        for (int b0 = 0; b0 < BB; b0 += nb) {
            const float* xin = ((cell == 0) ? x0 : (const float*)y) + (size_t)b0 * CS;
            float* yb = y + (size_t)b0 * CS;

            qkv_mfma_kernel<<<dim3(512, nb), 512, 0, stream>>>(xin, wc, bc, qf, kf, vf);

            if (cell == 0) {
                logits_part_kernel<16><<<dim3(NBLK, nb), 256, 0, stream>>>(qf, kf, part);
                reduce_softmax_kernel<16><<<dim3(16, nb), 256, 0, stream>>>(part, attnp, pbf);
                out16_kernel<<<dim3(2048, nb), 256, 0, stream>>>(xin, vf, attnp, gamma + cell, yb);
            } else {
                logits_part_kernel<64><<<dim3(NBLK, nb), 256, 0, stream>>>(qf, kf, part);
                reduce_softmax_kernel<64><<<dim3(64, nb), 256, 0, stream>>>(part, attnp, pbf);
                out64_mfma_kernel<<<dim3(512, nb), 256, 0, stream>>>(xin, vf, pbf, gamma + cell, yb);
            }
        }
    }
}

// Round 3
// 626.906 us; speedup vs baseline: 2.7117x; 1.0051x over previous
//
#include <hip/hip_runtime.h>

#define BB 4
#define CC 128
#define CQ 16
#define TDIM 16
#define SS 65536            /* T*W*H */
#define CS (CC*SS)          /* per-batch elements: 8388608 */
#define NBLK 256            /* stage-1 partial blocks */

typedef unsigned short u16;
typedef unsigned int   u32;

typedef __bf16 bf16x8v __attribute__((ext_vector_type(8)));
typedef float  floatx4v __attribute__((ext_vector_type(4)));

__device__ __forceinline__ u16 f2bf(float f) {
    u32 u = __float_as_uint(f);
    u32 r = (u + 0x7fffu + ((u >> 16) & 1u)) >> 16;
    return (u16)r;
}
__device__ __forceinline__ void unpack8(uint4 r, float* f) {
    f[0] = __uint_as_float(r.x << 16); f[1] = __uint_as_float(r.x & 0xffff0000u);
    f[2] = __uint_as_float(r.y << 16); f[3] = __uint_as_float(r.y & 0xffff0000u);
    f[4] = __uint_as_float(r.z << 16); f[5] = __uint_as_float(r.z & 0xffff0000u);
    f[6] = __uint_as_float(r.w << 16); f[7] = __uint_as_float(r.w & 0xffff0000u);
}
__device__ __forceinline__ bf16x8v ld_bf8(const void* p) {
    union { uint4 u; bf16x8v b; } x;
    x.u = *(const uint4*)p;
    return x.b;
}

// ---------------------------------------------------------------------------
// Weight pre-convert: all 3 cells' [Wq;Wk;Wv] -> bf16 [3][160][128] + fp32 bias[3][160]
// ---------------------------------------------------------------------------
__global__ __launch_bounds__(256) void wconv_kernel(
    const float* __restrict__ Wq, const float* __restrict__ Wk, const float* __restrict__ Wv,
    const float* __restrict__ bq, const float* __restrict__ bk, const float* __restrict__ bv,
    u16* __restrict__ wbf, float* __restrict__ bias)
{
    const int idx = blockIdx.x * 256 + threadIdx.x;     // < 61440
    const int cell = idx / 20480;
    const int j = idx - cell * 20480;
    const int o = j >> 7, c = j & 127;
    float v;
    if (o < 16)      v = Wq[(cell * 16 + o) * 128 + c];
    else if (o < 32) v = Wk[(cell * 16 + (o - 16)) * 128 + c];
    else             v = Wv[(cell * 128 + (o - 32)) * 128 + c];
    wbf[idx] = f2bf(v);
    if (idx < 480) {
        const int cl = idx / 160, oo = idx - cl * 160;
        float b = (oo < 16) ? bq[cl * 16 + oo]
                : (oo < 32) ? bk[cl * 16 + oo - 16]
                :             bv[cl * 128 + oo - 32];
        bias[idx] = b;
    }
}

// ---------------------------------------------------------------------------
// QKV 1x1 conv as bf16 MFMA GEMM: out(160,S) = W(160,128) x X(128,S).
// Block = 512 thr (8 waves), S-tile 128. Wave (mh = wv>>2, sq = wv&3):
// 5 m-tiles (rows mh*80..) x 32 s (2 subtiles of 16 at sq*32).
// LDS xT[s][c] bf16, byte = ((s<<8)+(c<<1)) ^ (swz(s)<<4),
// swz(s) = (s&7)^((s>>3)&7)  -> b128 frag reads 2-way-free, b16 stage writes ~4-way.
// Staging: contiguous float4 loads along s, element-wise transpose into LDS.
// Epilogue: q/k direct (64B rows); v bounced through LDS -> 256B-contiguous stores.
// ---------------------------------------------------------------------------
__global__ __launch_bounds__(512, 4) void qkv_mfma_kernel(
    const float* __restrict__ x,
    const u16* __restrict__ wbf, const float* __restrict__ bias,
    float* __restrict__ qf, float* __restrict__ kf, u16* __restrict__ vf)
{
    __shared__ u16 xT[128 * 128];                      // 32 KB
    const int t  = threadIdx.x;
    const int b  = blockIdx.y;
    const int s0 = blockIdx.x << 7;
    const float* xb = x + (size_t)b * CS;

    {   // stage: thread loads float4 (4 consecutive s, one c) -> 4 x ds_write_b16
        const int s4 = (t & 31) << 2;                  // 0..124
        const int cr = t >> 5;                         // 0..15
        const float* xs = xb + s0 + s4;
#pragma unroll
        for (int p = 0; p < 8; p++) {
            const int c = cr + p * 16;
            float4 f = *(const float4*)(xs + (size_t)c * SS);
            u16 h[4] = { f2bf(f.x), f2bf(f.y), f2bf(f.z), f2bf(f.w) };
#pragma unroll
            for (int j = 0; j < 4; j++) {
                const int sl = s4 + j;
                const u32 sw = (u32)(((sl & 7) ^ ((sl >> 3) & 7)) << 4);
                *(u16*)((char*)xT + ((((u32)sl << 8) + ((u32)c << 1)) ^ sw)) = h[j];
            }
        }
    }
    __syncthreads();

    const int lane = t & 63;
    const int wv   = t >> 6;           // 0..7
    const int mh   = wv >> 2;          // 0,1 -> rows mh*80..
    const int sq   = wv & 3;           // s offset sq*32
    const int ln15 = lane & 15;
    const int lhi  = lane >> 4;        // 0..3

    floatx4v acc[5][2] = {};

    const u16* abase = wbf + ((mh * 80 + ln15) << 7) + (lhi << 3);

#pragma unroll
    for (int ks = 0; ks < 4; ks++) {
        bf16x8v af[5];
#pragma unroll
        for (int mi = 0; mi < 5; mi++)
            af[mi] = ld_bf8(abase + (mi << 11) + (ks << 5));
#pragma unroll
        for (int nt = 0; nt < 2; nt++) {
            const int sl = sq * 32 + nt * 16 + ln15;
            const u32 sw = (u32)(((sl & 7) ^ ((sl >> 3) & 7)) << 4);
            const u32 off = (((u32)sl << 8) + (u32)((ks << 6) + (lhi << 4))) ^ sw;
            bf16x8v bf = ld_bf8((const char*)xT + off);
#pragma unroll
            for (int mi = 0; mi < 5; mi++)
                acc[mi][nt] = __builtin_amdgcn_mfma_f32_16x16x32_bf16(
                                  af[mi], bf, acc[mi][nt], 0, 0, 0);
        }
    }

    float* qb = qf + (size_t)b * ((size_t)CQ * SS);
    float* kb = kf + (size_t)b * ((size_t)CQ * SS);
    u16*   vb = vf + (size_t)b * (size_t)CS;

    // q/k direct stores (full-cache-line 64B row segments), before LDS reuse
    if (mh == 0) {
#pragma unroll
        for (int mi = 0; mi < 2; mi++) {
            const int o0 = mi * 16 + lhi * 4;          // q: 0..12, k: 16..28
            float bia[4];
            *(float4*)bia = *(const float4*)(bias + o0);
            float* base = (mi == 0) ? qb : kb;
            const int row0 = o0 & 15;
#pragma unroll
            for (int nt = 0; nt < 2; nt++) {
                const int s = s0 + sq * 32 + nt * 16 + ln15;
#pragma unroll
                for (int r = 0; r < 4; r++)
                    base[(size_t)(row0 + r) * SS + s] = acc[mi][nt][r] + bia[r];
            }
        }
    }
    __syncthreads();                   // all xT frag reads complete

    // v -> LDS bounce: (vc, sl) -> byte ((vc<<8)+(sl<<1)) ^ (swzv(vc)<<4)
#pragma unroll
    for (int mi = 0; mi < 5; mi++) {
        const int o0 = mh * 80 + mi * 16 + lhi * 4;
        if (o0 >= 32) {
            float bia[4];
            *(float4*)bia = *(const float4*)(bias + o0);
            const int vc0 = o0 - 32;
#pragma unroll
            for (int nt = 0; nt < 2; nt++) {
                const int sl = sq * 32 + nt * 16 + ln15;
#pragma unroll
                for (int r = 0; r < 4; r++) {
                    const int vc = vc0 + r;
                    const u32 sw = (u32)(((vc & 7) ^ ((vc >> 3) & 7)) << 4);
                    *(u16*)((char*)xT + ((((u32)vc << 8) + ((u32)sl << 1)) ^ sw))
                        = f2bf(acc[mi][nt][r] + bia[r]);
                }
            }
        }
    }
    __syncthreads();

    // cooperative contiguous v stores: 128 rows x 256B, 4 x 256B segs per instr
#pragma unroll
    for (int it = 0; it < 4; it++) {
        const int vc = (t >> 4) + it * 32;
        const u32 sw = (u32)(((vc & 7) ^ ((vc >> 3) & 7)) << 4);
        uint4 d = *(const uint4*)((char*)xT +
                      ((((u32)vc << 8) + ((u32)(t & 15) << 4)) ^ sw));
        *(uint4*)(vb + (size_t)vc * SS + s0 + ((t & 15) << 3)) = d;
    }
}

// ---------------------------------------------------------------------------
// Stage 1: per-block partial logits (layouts unchanged from verified version).
// part[blk]: A=64 -> t*16+j encodes (a1=t&63, a2=(t>>6)*16+j); A=16 -> t = a1*16+a2.
// ---------------------------------------------------------------------------
template <int A>
__global__ __launch_bounds__(256) void logits_part_kernel(
    const float* __restrict__ qf, const float* __restrict__ kf,
    float* __restrict__ part)
{
    constexpr int N = (CQ * SS) / A;
    constexpr int NCHUNK = N / NBLK;
    constexpr int NLOG = (NCHUNK == 64) ? 6 : 8;
    __shared__ float qs[A][NCHUNK + 1];
    __shared__ float ks[NCHUNK][A];
    const int t  = threadIdx.x;
    const int b  = blockIdx.y;
    const int n0 = blockIdx.x << NLOG;
    const float* qb = qf + (size_t)b * ((size_t)CQ * SS);
    const float* kb = kf + (size_t)b * ((size_t)CQ * SS);

    for (int idx = t; idx < A * NCHUNK; idx += 256) {
        int a1 = idx >> NLOG, n = idx & (NCHUNK - 1);
        qs[a1][n] = qb[(size_t)a1 * N + n0 + n];
    }
    float* ksf = &ks[0][0];
    for (int idx = t; idx < NCHUNK * A; idx += 256)
        ksf[idx] = kb[(size_t)n0 * A + idx];
    __syncthreads();

    float* pb = part + ((size_t)b * NBLK + blockIdx.x) * (A * A);

    if constexpr (A == 16) {
        int a1 = t >> 4, a2 = t & 15;
        float s = 0.f;
#pragma unroll 8
        for (int n = 0; n < NCHUNK; n++) s += qs[a1][n] * ks[n][a2];
        pb[t] = s;
    } else {
        int a1  = t & 63;
        int a2b = (t >> 6) * 16;
        float acc[16];
#pragma unroll
        for (int j = 0; j < 16; j++) acc[j] = 0.f;
        for (int n = 0; n < NCHUNK; n++) {
            float q = qs[a1][n];
#pragma unroll
            for (int j = 0; j < 16; j++) acc[j] += q * ks[n][a2b + j];
        }
        float* dst = pb + t * 16;
        *(float4*)(dst)      = make_float4(acc[0],  acc[1],  acc[2],  acc[3]);
        *(float4*)(dst + 4)  = make_float4(acc[4],  acc[5],  acc[6],  acc[7]);
        *(float4*)(dst + 8)  = make_float4(acc[8],  acc[9],  acc[10], acc[11]);
        *(float4*)(dst + 12) = make_float4(acc[12], acc[13], acc[14], acc[15]);
    }
}

// ---------------------------------------------------------------------------
// Stage 2: reduce partials + softmax. grid=(A, nb), block=256 (NG parallel groups).
// A=64 additionally emits bf16 attn (for the MFMA out kernel).
// ---------------------------------------------------------------------------
template <int A>
__global__ __launch_bounds__(256) void reduce_softmax_kernel(
    const float* __restrict__ part, float* __restrict__ attn, u16* __restrict__ pbf)
{
    constexpr int NG = 256 / A;              // 16 (A=16) or 4 (A=64)
    __shared__ float red[NG][A];
    const int a1 = blockIdx.x;
    const int b  = blockIdx.y;
    const int t  = threadIdx.x;
    const int a2 = t & (A - 1);
    const int g  = t >> ((A == 16) ? 4 : 6);
    const float* pb = part + (size_t)b * NBLK * (A * A);

    int off;
    if constexpr (A == 16) off = a1 * 16 + a2;
    else                   off = a1 * 16 + ((a2 >> 4) << 10) + (a2 & 15);

    float s0 = 0.f, s1 = 0.f, s2 = 0.f, s3 = 0.f;
    for (int blk = g; blk < NBLK; blk += 4 * NG) {
        s0 += pb[(size_t)(blk         ) * (A * A) + off];
        s1 += pb[(size_t)(blk +     NG) * (A * A) + off];
        s2 += pb[(size_t)(blk + 2 * NG) * (A * A) + off];
        s3 += pb[(size_t)(blk + 3 * NG) * (A * A) + off];
    }
    red[g][a2] = (s0 + s1) + (s2 + s3);
    __syncthreads();

    if (t < A) {
        float l = 0.f;
#pragma unroll
        for (int gg = 0; gg < NG; gg++) l += red[gg][t];
        float m = l;
#pragma unroll
        for (int o2 = A / 2; o2 > 0; o2 >>= 1) m = fmaxf(m, __shfl_xor(m, o2, 64));
        float e = expf(l - m);
        float s = e;
#pragma unroll
        for (int o2 = A / 2; o2 > 0; o2 >>= 1) s += __shfl_xor(s, o2, 64);
        const float p = e / s;
        attn[((size_t)b << 12) + a1 * A + t] = p;
        if constexpr (A == 64)
            pbf[((size_t)b << 12) + a1 * 64 + t] = f2bf(p);
    }
}

// ---------------------------------------------------------------------------
// Out, A=16 (cell T). Thread owns v-row m=(c,w,h), sweeps all 16 t outputs.
// ---------------------------------------------------------------------------
__global__ __launch_bounds__(256) void out16_kernel(
    const float* __restrict__ x, const u16* __restrict__ vf,
    const float* __restrict__ attn, const float* __restrict__ gptr,
    float* __restrict__ y)
{
    const int b = blockIdx.y;
    const u32 u = blockIdx.x * 256u + threadIdx.x;   // < CS/16 = 524288
    const float g = *gptr;
    const float* ab = attn + ((size_t)b << 12);
    const float* xb = x + (size_t)b * CS;
    float*       yb = y + (size_t)b * CS;
    const u16*   vr = vf + (size_t)b * CS + (size_t)u * 16;

    uint4 r0 = *(const uint4*)(vr);
    uint4 r1 = *(const uint4*)(vr + 8);
    float v0[8], v1[8];
    unpack8(r0, v0); unpack8(r1, v1);

    const size_t base = ((size_t)(u >> 12) << 16) + (u & 4095u);  // c*65536 + w*64 + h
#pragma unroll
    for (int tt = 0; tt < 16; tt++) {
        const float* ar = ab + tt * 16;
        float4 a0 = *(const float4*)(ar);
        float4 a1 = *(const float4*)(ar + 4);
        float4 a2 = *(const float4*)(ar + 8);
        float4 a3 = *(const float4*)(ar + 12);
        float acc = v0[0]*a0.x + v0[1]*a0.y + v0[2]*a0.z + v0[3]*a0.w
                  + v0[4]*a1.x + v0[5]*a1.y + v0[6]*a1.z + v0[7]*a1.w
                  + v1[0]*a2.x + v1[1]*a2.y + v1[2]*a2.z + v1[3]*a2.w
                  + v1[4]*a3.x + v1[5]*a3.y + v1[6]*a3.z + v1[7]*a3.w;
        const size_t i = base + ((size_t)tt << 12);
        yb[i] = g * acc + xb[i];
    }
}

// ---------------------------------------------------------------------------
// Out, A=64 (cells W,H) via MFMA: O[m][a1] = sum_a2 V[m][a2] * P[a1][a2].
// Verified in round 2. A-op = P (bf16, 64x64), B-op = V^T (rows of vf).
// ---------------------------------------------------------------------------
__global__ __launch_bounds__(256) void out64_mfma_kernel(
    const float* __restrict__ x, const u16* __restrict__ vf,
    const u16* __restrict__ pbf, const float* __restrict__ gptr,
    float* __restrict__ y)
{
    const int b = blockIdx.y;
    const int t = threadIdx.x;
    const float g = *gptr;
    const int lane = t & 63;
    const int ln15 = lane & 15;
    const int lhi  = lane >> 4;
    const int wv   = t >> 6;
    const int m0w  = blockIdx.x * 256 + wv * 64;

    const u16*   pb = pbf + ((size_t)b << 12);
    const u16*   vb = vf + (size_t)b * CS;
    const float* xb = x + (size_t)b * CS;
    float*       yb = y + (size_t)b * CS;

    // A-frags: P[a1 = sub*16 + ln15][k = ks*32 + lhi*8 + j]  (L1-hot, 8 x 16B)
    bf16x8v af[2][4];
#pragma unroll
    for (int ksi = 0; ksi < 2; ksi++)
#pragma unroll
        for (int sub = 0; sub < 4; sub++)
            af[ksi][sub] = ld_bf8(pb + (sub * 16 + ln15) * 64 + ksi * 32 + lhi * 8);

#pragma unroll
    for (int tile = 0; tile < 4; tile++) {
        const int m0 = m0w + tile * 16;
        const u16* vrow = vb + ((size_t)(m0 + ln15) << 6) + (lhi << 3);
        bf16x8v b0 = ld_bf8(vrow);          // k = 0..31  (per-lane map lhi*8+j)
        bf16x8v b1 = ld_bf8(vrow + 32);     // k = 32..63

        floatx4v acc[4] = {};
#pragma unroll
        for (int sub = 0; sub < 4; sub++) {
            acc[sub] = __builtin_amdgcn_mfma_f32_16x16x32_bf16(af[0][sub], b0, acc[sub], 0, 0, 0);
            acc[sub] = __builtin_amdgcn_mfma_f32_16x16x32_bf16(af[1][sub], b1, acc[sub], 0, 0, 0);
        }

        const int c   = m0 >> 10;
        const int ow  = ((m0 >> 6) & 15) * 4 + ((m0 & 63) >> 4);
        const size_t base = ((size_t)c << 16) + ((size_t)ow << 6) + (size_t)(ln15 << 2);
        const float* xbase = xb + base;
        float*       ybase = yb + base;
#pragma unroll
        for (int r = 0; r < 4; r++) {
            const int ot = lhi * 4 + r;                 // a1 & 15
            float4 xv = *(const float4*)(xbase + ((size_t)ot << 12));
            float4 o;
            o.x = g * acc[0][r] + xv.x;
            o.y = g * acc[1][r] + xv.y;
            o.z = g * acc[2][r] + xv.z;
            o.w = g * acc[3][r] + xv.w;
            *(float4*)(ybase + ((size_t)ot << 12)) = o;
        }
    }
}

// ---------------------------------------------------------------------------
// Workspace (nb batches resident): qf nb*4M | kf nb*4M | vf nb*16M |
// part nb*4M | attn nb*16K | pbf nb*8K | wbf3 120K | bias3 2K.
// nb=4 needs ~112.2 MiB; falls back to nb=1 if ws is smaller.
// ---------------------------------------------------------------------------
extern "C" void kernel_launch(void* const* d_in, const int* in_sizes, int n_in,
                              void* d_out, int out_size, void* d_ws, size_t ws_size,
                              hipStream_t stream)
{
    (void)in_sizes; (void)n_in; (void)out_size;
    const float* x0    = (const float*)d_in[0];
    const float* Wq    = (const float*)d_in[1];
    const float* bq    = (const float*)d_in[2];
    const float* Wk    = (const float*)d_in[3];
    const float* bk    = (const float*)d_in[4];
    const float* Wv    = (const float*)d_in[5];
    const float* bv    = (const float*)d_in[6];
    const float* gamma = (const float*)d_in[7];
    float* y = (float*)d_out;

    const size_t MiB = (size_t)1 << 20;
    const size_t need4 = 4 * (28 * MiB + 16384 + 8192) + 160 * 128 * 3 * 2 + 3 * 160 * 4;
    const int nb = (ws_size >= need4) ? 4 : 1;

    char* ws = (char*)d_ws;
    float* qf    = (float*)ws;
    float* kf    = (float*)(ws + (size_t)nb * 4  * MiB);
    u16*   vf    = (u16*)  (ws + (size_t)nb * 8  * MiB);
    float* part  = (float*)(ws + (size_t)nb * 24 * MiB);
    float* attnp = (float*)(ws + (size_t)nb * 28 * MiB);
    u16*   pbf   = (u16*)  (ws + (size_t)nb * 28 * MiB + (size_t)nb * 16384);
    u16*   wbf3  = (u16*)  (ws + (size_t)nb * 28 * MiB + (size_t)nb * (16384 + 8192));
    float* bias3 = (float*)(ws + (size_t)nb * 28 * MiB + (size_t)nb * (16384 + 8192)
                               + 160 * 128 * 3 * 2);

    wconv_kernel<<<240, 256, 0, stream>>>(Wq, Wk, Wv, bq, bk, bv, wbf3, bias3);

    for (int cell = 0; cell < 3; cell++) {
        const u16*   wc = wbf3  + (size_t)cell * 160 * 128;
        const float* bc = bias3 + (size_t)cell * 160;
        for (int b0 = 0; b0 < BB; b0 += nb) {
            const float* xin = ((cell == 0) ? x0 : (const float*)y) + (size_t)b0 * CS;
            float* yb = y + (size_t)b0 * CS;

            qkv_mfma_kernel<<<dim3(512, nb), 512, 0, stream>>>(xin, wc, bc, qf, kf, vf);

            if (cell == 0) {
                logits_part_kernel<16><<<dim3(NBLK, nb), 256, 0, stream>>>(qf, kf, part);
                reduce_softmax_kernel<16><<<dim3(16, nb), 256, 0, stream>>>(part, attnp, pbf);
                out16_kernel<<<dim3(2048, nb), 256, 0, stream>>>(xin, vf, attnp, gamma + cell, yb);
            } else {
                logits_part_kernel<64><<<dim3(NBLK, nb), 256, 0, stream>>>(qf, kf, part);
                reduce_softmax_kernel<64><<<dim3(64, nb), 256, 0, stream>>>(part, attnp, pbf);
                out64_mfma_kernel<<<dim3(512, nb), 256, 0, stream>>>(xin, vf, pbf, gamma + cell, yb);
            }
        }
    }
}